// Round 1
// 603.162 us; speedup vs baseline: 1.5509x; 1.5509x over previous
//
#include <hip/hip_runtime.h>
#include <hip/hip_bf16.h>

typedef __bf16 bf16;
typedef __bf16 bf16x8 __attribute__((ext_vector_type(8)));
typedef float f32x4 __attribute__((ext_vector_type(4)));

__device__ __forceinline__ float fast_exp2(float x) {
#if __has_builtin(__builtin_amdgcn_exp2f)
    return __builtin_amdgcn_exp2f(x);
#else
    return exp2f(x);
#endif
}

// ---------------------------------------------------------------------------
// load 8 consecutive elements as bf16x8, converting from f32 if needed
// ---------------------------------------------------------------------------
template <typename T>
__device__ __forceinline__ bf16x8 load8(const T* p);

template <>
__device__ __forceinline__ bf16x8 load8<bf16>(const bf16* p) {
    return *(const bf16x8*)p;
}

template <>
__device__ __forceinline__ bf16x8 load8<float>(const float* p) {
    float4 a = *(const float4*)p;
    float4 b = *(const float4*)(p + 4);
    bf16x8 r;
    r[0] = (bf16)a.x; r[1] = (bf16)a.y; r[2] = (bf16)a.z; r[3] = (bf16)a.w;
    r[4] = (bf16)b.x; r[5] = (bf16)b.y; r[6] = (bf16)b.z; r[7] = (bf16)b.w;
    return r;
}

// ---------------------------------------------------------------------------
// C[M x N] = A[M x K] * B[N x K]^T
// TA/TB in {bf16,float} (converted to bf16 for MFMA), f32 accum, TC out.
// 128x128 tile, BK=32, 4 waves (2x2), each wave 4x4 of 16x16x32 MFMA.
// EPI==0: plain   EPI==1: softplus(acc + bias_f32[col])
// EPI==2: out = gmul_bf16[row,col] * silu(acc)
// ---------------------------------------------------------------------------
#define KP 40   // padded LDS row stride (bf16 elems); 80 B rows, 16B-aligned

template <int EPI, typename TA, typename TB, typename TC>
__global__ __launch_bounds__(256, 2) void gemm_bt(
    const TA* __restrict__ A, int lda,
    const TB* __restrict__ B, int ldb,
    TC* __restrict__ C, int ldc,
    int K, int Neff, const float* __restrict__ bias,
    const bf16* __restrict__ gmul)
{
    __shared__ bf16 As[128 * KP];
    __shared__ bf16 Bs[128 * KP];

    const int tid  = threadIdx.x;
    const int lane = tid & 63;
    const int wave = tid >> 6;
    const int quad = lane >> 4;
    const int l16  = lane & 15;
    const int wm   = (wave >> 1) << 6;
    const int wn   = (wave & 1) << 6;
    const int bm   = blockIdx.x << 7;
    const int bn   = blockIdx.y << 7;

    const int srow = tid >> 2;
    const int scol = (tid & 3) << 3;

    const TA* Ag0 = A + (size_t)(bm + srow) * lda + scol;
    const TA* Ag1 = Ag0 + (size_t)lda * 64;
    int br0 = bn + srow;      br0 = br0 < Neff ? br0 : Neff - 1;
    int br1 = bn + srow + 64; br1 = br1 < Neff ? br1 : Neff - 1;
    const TB* Bg0 = B + (size_t)br0 * ldb + scol;
    const TB* Bg1 = B + (size_t)br1 * ldb + scol;

    bf16* Asd = As + srow * KP + scol;
    bf16* Bsd = Bs + srow * KP + scol;

    f32x4 acc[4][4] = {};

    for (int k0 = 0; k0 < K; k0 += 32) {
        bf16x8 a0 = load8<TA>(Ag0 + k0);
        bf16x8 a1 = load8<TA>(Ag1 + k0);
        bf16x8 b0 = load8<TB>(Bg0 + k0);
        bf16x8 b1 = load8<TB>(Bg1 + k0);

        if (k0) __syncthreads();
        *(bf16x8*)(Asd)           = a0;
        *(bf16x8*)(Asd + 64 * KP) = a1;
        *(bf16x8*)(Bsd)           = b0;
        *(bf16x8*)(Bsd + 64 * KP) = b1;
        __syncthreads();

        bf16x8 af[4], bfr[4];
#pragma unroll
        for (int i = 0; i < 4; ++i) {
            af[i]  = *(const bf16x8*)(As + (wm + i * 16 + l16) * KP + quad * 8);
            bfr[i] = *(const bf16x8*)(Bs + (wn + i * 16 + l16) * KP + quad * 8);
        }
#pragma unroll
        for (int mi = 0; mi < 4; ++mi)
#pragma unroll
            for (int ni = 0; ni < 4; ++ni)
                acc[mi][ni] = __builtin_amdgcn_mfma_f32_16x16x32_bf16(
                    af[mi], bfr[ni], acc[mi][ni], 0, 0, 0);
    }

    // C/D layout: row = quad*4 + r, col = l16  (m89-verified)
#pragma unroll
    for (int mi = 0; mi < 4; ++mi) {
        const int row = bm + wm + mi * 16 + quad * 4;
#pragma unroll
        for (int ni = 0; ni < 4; ++ni) {
            const int col = bn + wn + ni * 16 + l16;
            if (col < Neff) {
                float bc = (EPI == 1) ? bias[col] : 0.f;
#pragma unroll
                for (int r = 0; r < 4; ++r) {
                    float v = acc[mi][ni][r];
                    if (EPI == 1) {
                        v += bc;
                        v = (v > 15.f) ? v : log1pf(__expf(v));
                    } else if (EPI == 2) {
                        float g = v / (1.f + __expf(-v));   // silu(z)
                        v = (float)gmul[(size_t)(row + r) * ldc + col] * g;
                    }
                    C[(size_t)(row + r) * ldc + col] = (TC)v;
                }
            }
        }
    }
}

// ---------------------------------------------------------------------------
// causal depthwise conv (k=4, left pad 3) + bias + SiLU: xh bf16 -> xc bf16
// ---------------------------------------------------------------------------
__global__ __launch_bounds__(256) void conv_kernel(
    const bf16* __restrict__ xh, const float* __restrict__ cw,
    const float* __restrict__ cb, bf16* __restrict__ xc)
{
    const int bt = blockIdx.x;
    const int t  = bt & 2047;
    const int d  = threadIdx.x * 8;

    float4 wv[8];           // wv[i] = taps 0..3 of channel d+i
#pragma unroll
    for (int i = 0; i < 8; ++i)
        wv[i] = *(const float4*)(cw + (d + i) * 4);

    float4 cb0 = *(const float4*)(cb + d);
    float4 cb1 = *(const float4*)(cb + d + 4);
    float acc[8] = { cb0.x, cb0.y, cb0.z, cb0.w, cb1.x, cb1.y, cb1.z, cb1.w };

#pragma unroll
    for (int j = 0; j < 4; ++j) {
        int ts = t - 3 + j;
        if (ts >= 0) {
            bf16x8 v = *(const bf16x8*)(xh + (size_t)(bt - (3 - j)) * 2048 + d);
#pragma unroll
            for (int i = 0; i < 8; ++i) {
                float w = (j == 0) ? wv[i].x : (j == 1) ? wv[i].y
                        : (j == 2) ? wv[i].z : wv[i].w;
                acc[i] += w * (float)v[i];
            }
        }
    }

    bf16x8 o;
#pragma unroll
    for (int i = 0; i < 8; ++i) {
        float s = acc[i];
        o[i] = (bf16)(s / (1.f + __expf(-s)));
    }
    *(bf16x8*)(xc + (size_t)bt * 2048 + d) = o;
}

// ---------------------------------------------------------------------------
// Chunk-parallel selective scan (NC=32 chunks x TC=64 t).
// NEW layout: thread = (b, c, d); all 16 states n kept in registers.
//   - x/dt loaded ONCE per (t,d) (coalesced 128B/wave), not 16x redundantly
//   - B[16]/C[16] are wave-uniform contiguous 16B vector loads (broadcast)
//   - n-reduction = 15 in-register FMAs (no 128-lane-op shuffle tree)
//   - exp via bare v_exp_f32: A2[n] = A[n]*log2(e) premultiplied per thread
// Hbuf/Abuf layout: (b, c, d, n) -> 16 contiguous values per thread.
// scan_p2 is layout-agnostic (flat 32768 inner index), unchanged.
// ---------------------------------------------------------------------------
__global__ __launch_bounds__(256, 4) void scan_p1(
    const bf16* __restrict__ delta, const bf16* __restrict__ dbc,
    const float* __restrict__ A_raw, const bf16* __restrict__ xc,
    float* __restrict__ Hbuf, bf16* __restrict__ Abuf)
{
    const int d = (blockIdx.x << 8) + threadIdx.x;
    const int b = blockIdx.y;
    const int c = blockIdx.z;

    float A2[16];           // A[n] * log2(e)
#pragma unroll
    for (int n = 0; n < 16; ++n)
        A2[n] = -__expf(A_raw[n * 2048 + d]) * 1.44269504f;

    float h[16];
#pragma unroll
    for (int n = 0; n < 16; ++n) h[n] = 0.f;
    float sdt = 0.f;

    const size_t xbase = ((size_t)(b * 2048 + c * 64)) * 2048 + d;
    const bf16* xp = xc + xbase;
    const bf16* dp = delta + xbase;
    const bf16* bp = dbc + ((size_t)(b * 2048 + c * 64)) * 96 + 64;

    bf16 xr = xp[0], dr = dp[0];
    bf16x8 B0 = *(const bf16x8*)(bp);
    bf16x8 B1 = *(const bf16x8*)(bp + 8);

#pragma unroll 4
    for (int t = 0; t < 64; ++t) {
        const float x  = (float)xr;
        const float dt = (float)dr;
        const bf16x8 Bl = B0, Bh = B1;
        if (t < 63) {
            xr = xp[(size_t)(t + 1) * 2048];
            dr = dp[(size_t)(t + 1) * 2048];
            const bf16* nb = bp + (size_t)(t + 1) * 96;
            B0 = *(const bf16x8*)nb;
            B1 = *(const bf16x8*)(nb + 8);
        }
        const float dx = dt * x;
        sdt += dt;
#pragma unroll
        for (int n = 0; n < 8; ++n) {
            float e = fast_exp2(dt * A2[n]);
            h[n] = e * h[n] + (float)Bl[n] * dx;
        }
#pragma unroll
        for (int n = 0; n < 8; ++n) {
            float e = fast_exp2(dt * A2[n + 8]);
            h[n + 8] = e * h[n + 8] + (float)Bh[n] * dx;
        }
    }

    const size_t hbase = (((size_t)b * 32 + c) * 2048 + d) * 16;
    f32x4* Hp = (f32x4*)(Hbuf + hbase);
#pragma unroll
    for (int r = 0; r < 4; ++r) {
        f32x4 v;
        v[0] = h[r * 4]; v[1] = h[r * 4 + 1];
        v[2] = h[r * 4 + 2]; v[3] = h[r * 4 + 3];
        Hp[r] = v;
    }
    bf16x8 a0, a1;
#pragma unroll
    for (int n = 0; n < 8; ++n) {
        a0[n] = (bf16)fast_exp2(A2[n] * sdt);
        a1[n] = (bf16)fast_exp2(A2[n + 8] * sdt);
    }
    *(bf16x8*)(Abuf + hbase) = a0;
    *(bf16x8*)(Abuf + hbase + 8) = a1;
}

__global__ __launch_bounds__(256) void scan_p2(
    float* __restrict__ Hbuf, const bf16* __restrict__ Abuf)
{
    const int id  = blockIdx.x * 256 + threadIdx.x;   // 131072 = b*32768+(d*16+n)
    const int b   = id >> 15;
    const int rem = id & 32767;
    const size_t base = (size_t)b * 32 * 32768 + rem;  // chunk stride 32768

    float Hv[32]; bf16 Av[32];
#pragma unroll
    for (int c = 0; c < 32; ++c) {
        Hv[c] = Hbuf[base + (size_t)c * 32768];
        Av[c] = Abuf[base + (size_t)c * 32768];
    }
    float ht = Hv[0];                      // H~_0 = H_0 (already stored)
#pragma unroll
    for (int c = 1; c < 32; ++c) {
        ht = Hv[c] + (float)Av[c] * ht;
        Hbuf[base + (size_t)c * 32768] = ht;
    }
}

__global__ __launch_bounds__(256, 4) void scan_p3(
    const bf16* __restrict__ delta, const bf16* __restrict__ dbc,
    const float* __restrict__ A_raw, const float* __restrict__ Dvec,
    const float* __restrict__ Hbuf, const bf16* xc, bf16* ry)
{
    const int d = (blockIdx.x << 8) + threadIdx.x;
    const int b = blockIdx.y;
    const int c = blockIdx.z;

    float A2[16];
#pragma unroll
    for (int n = 0; n < 16; ++n)
        A2[n] = -__expf(A_raw[n * 2048 + d]) * 1.44269504f;
    const float Dd = Dvec[d];

    float h[16];
    if (c > 0) {
        const f32x4* Hp = (const f32x4*)(
            Hbuf + (((size_t)b * 32 + (c - 1)) * 2048 + d) * 16);
#pragma unroll
        for (int r = 0; r < 4; ++r) {
            f32x4 v = Hp[r];
            h[r * 4] = v[0]; h[r * 4 + 1] = v[1];
            h[r * 4 + 2] = v[2]; h[r * 4 + 3] = v[3];
        }
    } else {
#pragma unroll
        for (int n = 0; n < 16; ++n) h[n] = 0.f;
    }

    const size_t xbase = ((size_t)(b * 2048 + c * 64)) * 2048 + d;
    const bf16* xp = xc + xbase;
    const bf16* dp = delta + xbase;
    const bf16* bp = dbc + ((size_t)(b * 2048 + c * 64)) * 96 + 64;
    bf16* yp = ry + xbase;

    bf16 xr = xp[0], dr = dp[0];
    bf16x8 B0 = *(const bf16x8*)(bp);
    bf16x8 B1 = *(const bf16x8*)(bp + 8);
    bf16x8 C0 = *(const bf16x8*)(bp + 16);
    bf16x8 C1 = *(const bf16x8*)(bp + 24);

#pragma unroll 4
    for (int t = 0; t < 64; ++t) {
        const float x  = (float)xr;
        const float dt = (float)dr;
        const bf16x8 Bl = B0, Bh = B1, Cl = C0, Ch = C1;
        if (t < 63) {
            xr = xp[(size_t)(t + 1) * 2048];
            dr = dp[(size_t)(t + 1) * 2048];
            const bf16* nb = bp + (size_t)(t + 1) * 96;
            B0 = *(const bf16x8*)nb;
            B1 = *(const bf16x8*)(nb + 8);
            C0 = *(const bf16x8*)(nb + 16);
            C1 = *(const bf16x8*)(nb + 24);
        }
        const float dx = dt * x;
        float y = Dd * x;
#pragma unroll
        for (int n = 0; n < 8; ++n) {
            float e = fast_exp2(dt * A2[n]);
            h[n] = e * h[n] + (float)Bl[n] * dx;
            y += (float)Cl[n] * h[n];
        }
#pragma unroll
        for (int n = 0; n < 8; ++n) {
            float e = fast_exp2(dt * A2[n + 8]);
            h[n + 8] = e * h[n + 8] + (float)Bh[n] * dx;
            y += (float)Ch[n] * h[n + 8];
        }
        yp[(size_t)t * 2048] = (bf16)y;
    }
}

// ---------------------------------------------------------------------------
// launch.  Inputs: f32. Output: f32.  Workspace (>=64 MiB proven):
//   buf0 [0,   32Mi): xh -> delta -> y      (bf16)
//   buf1 [32Mi,64Mi): xc -> ry (in place)   (bf16)
// d_out (32 MiB, dead until gemm7):
//   dbc bf16 @0 (1.5 MiB) | Hbuf f32 @2Mi (16 MiB) | Abuf bf16 @20Mi (8 MiB)
// z never materialized: gating fused into the z-GEMM epilogue (EPI=2).
// ---------------------------------------------------------------------------
extern "C" void kernel_launch(void* const* d_in, const int* in_sizes, int n_in,
                              void* d_out, int out_size, void* d_ws, size_t ws_size,
                              hipStream_t stream)
{
    const float* x      = (const float*)d_in[0];
    const float* W_in   = (const float*)d_in[1];
    const float* conv_w = (const float*)d_in[2];
    const float* conv_b = (const float*)d_in[3];
    const float* W_x    = (const float*)d_in[4];
    const float* W_dt   = (const float*)d_in[5];
    const float* b_dt   = (const float*)d_in[6];
    const float* A_raw  = (const float*)d_in[7];
    const float* Dvec   = (const float*)d_in[8];
    const float* W_out  = (const float*)d_in[9];
    float* out = (float*)d_out;

    char* ws = (char*)d_ws;
    bf16*  buf0 = (bf16*)(ws + 0);          // xh -> delta -> y
    bf16*  buf1 = (bf16*)(ws + 33554432);   // xc -> ry
    bf16*  dbc  = (bf16*)d_out;
    float* Hbuf = (float*)((char*)d_out + 2097152);
    bf16*  Abuf = (bf16*)((char*)d_out + 20971520);

    // 1) xh = x @ W_in[:2048]^T          M=8192 N=2048 K=1024
    gemm_bt<0, float, float, bf16><<<dim3(64, 16), 256, 0, stream>>>(
        x, 1024, W_in, 1024, buf0, 2048, 1024, 2048, nullptr, nullptr);
    // 2) xc = silu(causal_conv(xh) + cb)
    conv_kernel<<<dim3(8192), 256, 0, stream>>>(buf0, conv_w, conv_b, buf1);
    // 3) dbc = xc @ W_x^T                M=8192 N=96 K=2048
    gemm_bt<0, bf16, float, bf16><<<dim3(64, 1), 256, 0, stream>>>(
        buf1, 2048, W_x, 2048, dbc, 96, 2048, 96, nullptr, nullptr);
    // 4) delta = softplus(dt @ W_dt^T + b_dt)   (lda=96, K=64)
    gemm_bt<1, bf16, float, bf16><<<dim3(64, 16), 256, 0, stream>>>(
        dbc, 96, W_dt, 64, buf0, 2048, 64, 2048, b_dt, nullptr);
    // 5) chunk-parallel scan -> ry (ungated), in place over xc
    scan_p1<<<dim3(8, 4, 32), 256, 0, stream>>>(
        buf0, dbc, A_raw, buf1, Hbuf, Abuf);
    scan_p2<<<dim3(512), 256, 0, stream>>>(Hbuf, Abuf);
    scan_p3<<<dim3(8, 4, 32), 256, 0, stream>>>(
        buf0, dbc, A_raw, Dvec, Hbuf, buf1, buf1);
    // 6) y = ry * silu(x @ W_in[2048:]^T)   (fused z-GEMM + gate)
    gemm_bt<2, float, float, bf16><<<dim3(64, 16), 256, 0, stream>>>(
        x, 1024, W_in + (size_t)2048 * 1024, 1024, buf0, 2048, 1024, 2048,
        nullptr, buf1);
    // 7) out = y @ W_out^T  (f32 store)  M=8192 N=1024 K=2048
    gemm_bt<0, bf16, float, float><<<dim3(64, 8), 256, 0, stream>>>(
        buf0, 2048, W_out, 2048, out, 1024, 2048, 1024, nullptr, nullptr);
}

// Round 2
// 519.663 us; speedup vs baseline: 1.8002x; 1.1607x over previous
//
#include <hip/hip_runtime.h>
#include <hip/hip_bf16.h>

typedef __bf16 bf16;
typedef __bf16 bf16x4 __attribute__((ext_vector_type(4)));
typedef __bf16 bf16x8 __attribute__((ext_vector_type(8)));
typedef float f32x4 __attribute__((ext_vector_type(4)));

__device__ __forceinline__ float fast_exp2(float x) {
#if __has_builtin(__builtin_amdgcn_exp2f)
    return __builtin_amdgcn_exp2f(x);
#else
    return exp2f(x);
#endif
}

// async global->LDS, 16B per lane. lds base must be wave-uniform; the HW
// writes lds + lane*16; the GLOBAL address is per-lane. (m97 pattern)
__device__ __forceinline__ void gload16(bf16* lds, const bf16* g) {
    __builtin_amdgcn_global_load_lds(
        (const __attribute__((address_space(1))) void*)g,
        (__attribute__((address_space(3))) void*)lds,
        16, 0, 0);
}

// ---------------------------------------------------------------------------
// f32 -> bf16 vectorized cast (8 elems / thread)
// ---------------------------------------------------------------------------
__device__ __forceinline__ bf16x8 cvt8(const float* p) {
    float4 a = *(const float4*)p;
    float4 b = *(const float4*)(p + 4);
    bf16x8 r;
    r[0] = (bf16)a.x; r[1] = (bf16)a.y; r[2] = (bf16)a.z; r[3] = (bf16)a.w;
    r[4] = (bf16)b.x; r[5] = (bf16)b.y; r[6] = (bf16)b.z; r[7] = (bf16)b.w;
    return r;
}

__global__ __launch_bounds__(256) void cvt_bf16(
    const float* __restrict__ in, bf16* __restrict__ out, int n8)
{
    int i = blockIdx.x * 256 + threadIdx.x;
    if (i < n8)
        *(bf16x8*)(out + (size_t)i * 8) = cvt8(in + (size_t)i * 8);
}

// ---------------------------------------------------------------------------
// C[M x N] = A[M x K] * B[N x K]^T   (A,B bf16; f32 accum; TC out)
// m97 structure: 128x128 tile, BK=32, linear LDS [128][32] (64B rows),
// global_load_lds dwordx4 staging (4 issues/thread/K-step), 2-barrier loop,
// 4 waves (2x2), each wave 4x4 of 16x16x32 MFMA.
// EPI==0: plain   EPI==1: softplus(acc + bias_f32[col])
// EPI==2: out = gmul_bf16[row,col] * silu(acc)
// grid.z splits K: block z computes K range [z*K, (z+1)*K), stores to
// C + z*zstride (f32 partials for split-K callers; zstride=0 otherwise).
// ---------------------------------------------------------------------------
template <int EPI, typename TC>
__global__ __launch_bounds__(256, 2) void gemm_bt(
    const bf16* __restrict__ A, int lda,
    const bf16* __restrict__ B, int ldb,
    TC* __restrict__ C, int ldc,
    int K, int Neff, const float* __restrict__ bias,
    const bf16* __restrict__ gmul, size_t zstride)
{
    __shared__ bf16 As[128 * 32];
    __shared__ bf16 Bs[128 * 32];

    const int tid  = threadIdx.x;
    const int lane = tid & 63;
    const int wave = tid >> 6;
    const int quad = lane >> 4;
    const int l16  = lane & 15;
    const int wm   = (wave >> 1) << 6;
    const int wn   = (wave & 1) << 6;
    const int bm   = blockIdx.x << 7;
    const int bn   = blockIdx.y << 7;
    const int kb   = blockIdx.z * K;

    // staging map: round r in {0,1}, wave w covers LDS rows [(r*4+w)*16,+16)
    // lane l -> row +(l>>2), col (l&3)*8   (lds dest = uniform base + l*16B)
    const int srow = (wave << 4) + (lane >> 2);
    const int scol = (lane & 3) << 3;

    const bf16* Ag0 = A + (size_t)(bm + srow) * lda + kb + scol;
    const bf16* Ag1 = Ag0 + (size_t)lda * 64;
    int br0 = bn + srow;      br0 = br0 < Neff ? br0 : Neff - 1;
    int br1 = bn + srow + 64; br1 = br1 < Neff ? br1 : Neff - 1;
    const bf16* Bg0 = B + (size_t)br0 * ldb + kb + scol;
    const bf16* Bg1 = B + (size_t)br1 * ldb + kb + scol;

    bf16* Asd0 = As + wave * 512;           // wave-uniform LDS bases
    bf16* Asd1 = As + wave * 512 + 2048;
    bf16* Bsd0 = Bs + wave * 512;
    bf16* Bsd1 = Bs + wave * 512 + 2048;

    f32x4 acc[4][4] = {};

    for (int k0 = 0; k0 < K; k0 += 32) {
        if (k0) __syncthreads();            // protect LDS from overwrite
        gload16(Asd0, Ag0 + k0);
        gload16(Asd1, Ag1 + k0);
        gload16(Bsd0, Bg0 + k0);
        gload16(Bsd1, Bg1 + k0);
        __syncthreads();                    // drains vmcnt before barrier

        bf16x8 af[4], bfr[4];
#pragma unroll
        for (int i = 0; i < 4; ++i) {
            af[i]  = *(const bf16x8*)(As + (wm + i * 16 + l16) * 32 + quad * 8);
            bfr[i] = *(const bf16x8*)(Bs + (wn + i * 16 + l16) * 32 + quad * 8);
        }
#pragma unroll
        for (int mi = 0; mi < 4; ++mi)
#pragma unroll
            for (int ni = 0; ni < 4; ++ni)
                acc[mi][ni] = __builtin_amdgcn_mfma_f32_16x16x32_bf16(
                    af[mi], bfr[ni], acc[mi][ni], 0, 0, 0);
    }

    TC* Cz = C + (size_t)blockIdx.z * zstride;

    // C/D layout: row = quad*4 + r, col = l16  (m89-verified)
#pragma unroll
    for (int mi = 0; mi < 4; ++mi) {
        const int row = bm + wm + mi * 16 + quad * 4;
#pragma unroll
        for (int ni = 0; ni < 4; ++ni) {
            const int col = bn + wn + ni * 16 + l16;
            if (col < Neff) {
                float bc = (EPI == 1) ? bias[col] : 0.f;
#pragma unroll
                for (int r = 0; r < 4; ++r) {
                    float v = acc[mi][ni][r];
                    if (EPI == 1) {
                        v += bc;
                        v = (v > 15.f) ? v : log1pf(__expf(v));
                    } else if (EPI == 2) {
                        float g = v / (1.f + __expf(-v));   // silu(z)
                        v = (float)gmul[(size_t)(row + r) * ldc + col] * g;
                    }
                    Cz[(size_t)(row + r) * ldc + col] = (TC)v;
                }
            }
        }
    }
}

// ---------------------------------------------------------------------------
// split-K reduce: dbc[i] = bf16(sum_z P[z][i]),  n = 8192*96, 4 splits
// ---------------------------------------------------------------------------
__global__ __launch_bounds__(256) void reduce_dbc(
    const float* __restrict__ P, bf16* __restrict__ dbc)
{
    const size_t i = ((size_t)blockIdx.x * 256 + threadIdx.x) * 4;
    f32x4 s = *(const f32x4*)(P + i);
#pragma unroll
    for (int z = 1; z < 4; ++z) {
        f32x4 p = *(const f32x4*)(P + (size_t)z * 786432 + i);
        s[0] += p[0]; s[1] += p[1]; s[2] += p[2]; s[3] += p[3];
    }
    bf16x4 o;
    o[0] = (bf16)s[0]; o[1] = (bf16)s[1]; o[2] = (bf16)s[2]; o[3] = (bf16)s[3];
    *(bf16x4*)(dbc + i) = o;
}

// ---------------------------------------------------------------------------
// causal depthwise conv (k=4, left pad 3) + bias + SiLU: xh bf16 -> xc bf16
// ---------------------------------------------------------------------------
__global__ __launch_bounds__(256) void conv_kernel(
    const bf16* __restrict__ xh, const float* __restrict__ cw,
    const float* __restrict__ cb, bf16* __restrict__ xc)
{
    const int bt = blockIdx.x;
    const int t  = bt & 2047;
    const int d  = threadIdx.x * 8;

    float4 wv[8];           // wv[i] = taps 0..3 of channel d+i
#pragma unroll
    for (int i = 0; i < 8; ++i)
        wv[i] = *(const float4*)(cw + (d + i) * 4);

    float4 cb0 = *(const float4*)(cb + d);
    float4 cb1 = *(const float4*)(cb + d + 4);
    float acc[8] = { cb0.x, cb0.y, cb0.z, cb0.w, cb1.x, cb1.y, cb1.z, cb1.w };

#pragma unroll
    for (int j = 0; j < 4; ++j) {
        int ts = t - 3 + j;
        if (ts >= 0) {
            bf16x8 v = *(const bf16x8*)(xh + (size_t)(bt - (3 - j)) * 2048 + d);
#pragma unroll
            for (int i = 0; i < 8; ++i) {
                float w = (j == 0) ? wv[i].x : (j == 1) ? wv[i].y
                        : (j == 2) ? wv[i].z : wv[i].w;
                acc[i] += w * (float)v[i];
            }
        }
    }

    bf16x8 o;
#pragma unroll
    for (int i = 0; i < 8; ++i) {
        float s = acc[i];
        o[i] = (bf16)(s / (1.f + __expf(-s)));
    }
    *(bf16x8*)(xc + (size_t)bt * 2048 + d) = o;
}

// ---------------------------------------------------------------------------
// Chunk-parallel selective scan, NC=16 chunks x TC=128 t.
// thread = (b, c, d); all 16 states n in registers (x/dt loaded once per
// (t,d), B/C as contiguous 16B broadcast loads, n-reduce in-register,
// bare v_exp_f32 via premultiplied A*log2e).
// Hbuf/Abuf layout: (b, c, d, n).
// ---------------------------------------------------------------------------
__global__ __launch_bounds__(256, 4) void scan_p1(
    const bf16* __restrict__ delta, const bf16* __restrict__ dbc,
    const float* __restrict__ A_raw, const bf16* __restrict__ xc,
    float* __restrict__ Hbuf, bf16* __restrict__ Abuf)
{
    const int d = (blockIdx.x << 8) + threadIdx.x;
    const int b = blockIdx.y;
    const int c = blockIdx.z;

    float A2[16];           // A[n] * log2(e)
#pragma unroll
    for (int n = 0; n < 16; ++n)
        A2[n] = -__expf(A_raw[n * 2048 + d]) * 1.44269504f;

    float h[16];
#pragma unroll
    for (int n = 0; n < 16; ++n) h[n] = 0.f;
    float sdt = 0.f;

    const size_t xbase = ((size_t)(b * 2048 + c * 128)) * 2048 + d;
    const bf16* xp = xc + xbase;
    const bf16* dp = delta + xbase;
    const bf16* bp = dbc + ((size_t)(b * 2048 + c * 128)) * 96 + 64;

    bf16 xr = xp[0], dr = dp[0];
    bf16x8 B0 = *(const bf16x8*)(bp);
    bf16x8 B1 = *(const bf16x8*)(bp + 8);

#pragma unroll 4
    for (int t = 0; t < 128; ++t) {
        const float x  = (float)xr;
        const float dt = (float)dr;
        const bf16x8 Bl = B0, Bh = B1;
        if (t < 127) {
            xr = xp[(size_t)(t + 1) * 2048];
            dr = dp[(size_t)(t + 1) * 2048];
            const bf16* nb = bp + (size_t)(t + 1) * 96;
            B0 = *(const bf16x8*)nb;
            B1 = *(const bf16x8*)(nb + 8);
        }
        const float dx = dt * x;
        sdt += dt;
#pragma unroll
        for (int n = 0; n < 8; ++n) {
            float e = fast_exp2(dt * A2[n]);
            h[n] = e * h[n] + (float)Bl[n] * dx;
        }
#pragma unroll
        for (int n = 0; n < 8; ++n) {
            float e = fast_exp2(dt * A2[n + 8]);
            h[n + 8] = e * h[n + 8] + (float)Bh[n] * dx;
        }
    }

    const size_t hbase = (((size_t)b * 16 + c) * 2048 + d) * 16;
    f32x4* Hp = (f32x4*)(Hbuf + hbase);
#pragma unroll
    for (int r = 0; r < 4; ++r) {
        f32x4 v;
        v[0] = h[r * 4]; v[1] = h[r * 4 + 1];
        v[2] = h[r * 4 + 2]; v[3] = h[r * 4 + 3];
        Hp[r] = v;
    }
    bf16x8 a0, a1;
#pragma unroll
    for (int n = 0; n < 8; ++n) {
        a0[n] = (bf16)fast_exp2(A2[n] * sdt);
        a1[n] = (bf16)fast_exp2(A2[n + 8] * sdt);
    }
    *(bf16x8*)(Abuf + hbase) = a0;
    *(bf16x8*)(Abuf + hbase + 8) = a1;
}

__global__ __launch_bounds__(256) void scan_p2(
    float* __restrict__ Hbuf, const bf16* __restrict__ Abuf)
{
    const int id  = blockIdx.x * 256 + threadIdx.x;   // 131072 = b*32768+(d*16+n)
    const int b   = id >> 15;
    const int rem = id & 32767;
    const size_t base = (size_t)b * 16 * 32768 + rem;  // chunk stride 32768

    float Hv[16]; bf16 Av[16];
#pragma unroll
    for (int c = 0; c < 16; ++c) {
        Hv[c] = Hbuf[base + (size_t)c * 32768];
        Av[c] = Abuf[base + (size_t)c * 32768];
    }
    float ht = Hv[0];                      // H~_0 = H_0 (already stored)
#pragma unroll
    for (int c = 1; c < 16; ++c) {
        ht = Hv[c] + (float)Av[c] * ht;
        Hbuf[base + (size_t)c * 32768] = ht;
    }
}

__global__ __launch_bounds__(256, 4) void scan_p3(
    const bf16* __restrict__ delta, const bf16* __restrict__ dbc,
    const float* __restrict__ A_raw, const float* __restrict__ Dvec,
    const float* __restrict__ Hbuf, const bf16* xc, bf16* ry)
{
    const int d = (blockIdx.x << 8) + threadIdx.x;
    const int b = blockIdx.y;
    const int c = blockIdx.z;

    float A2[16];
#pragma unroll
    for (int n = 0; n < 16; ++n)
        A2[n] = -__expf(A_raw[n * 2048 + d]) * 1.44269504f;
    const float Dd = Dvec[d];

    float h[16];
    if (c > 0) {
        const f32x4* Hp = (const f32x4*)(
            Hbuf + (((size_t)b * 16 + (c - 1)) * 2048 + d) * 16);
#pragma unroll
        for (int r = 0; r < 4; ++r) {
            f32x4 v = Hp[r];
            h[r * 4] = v[0]; h[r * 4 + 1] = v[1];
            h[r * 4 + 2] = v[2]; h[r * 4 + 3] = v[3];
        }
    } else {
#pragma unroll
        for (int n = 0; n < 16; ++n) h[n] = 0.f;
    }

    const size_t xbase = ((size_t)(b * 2048 + c * 128)) * 2048 + d;
    const bf16* xp = xc + xbase;
    const bf16* dp = delta + xbase;
    const bf16* bp = dbc + ((size_t)(b * 2048 + c * 128)) * 96 + 64;
    bf16* yp = ry + xbase;

    bf16 xr = xp[0], dr = dp[0];
    bf16x8 B0 = *(const bf16x8*)(bp);
    bf16x8 B1 = *(const bf16x8*)(bp + 8);
    bf16x8 C0 = *(const bf16x8*)(bp + 16);
    bf16x8 C1 = *(const bf16x8*)(bp + 24);

#pragma unroll 4
    for (int t = 0; t < 128; ++t) {
        const float x  = (float)xr;
        const float dt = (float)dr;
        const bf16x8 Bl = B0, Bh = B1, Cl = C0, Ch = C1;
        if (t < 127) {
            xr = xp[(size_t)(t + 1) * 2048];
            dr = dp[(size_t)(t + 1) * 2048];
            const bf16* nb = bp + (size_t)(t + 1) * 96;
            B0 = *(const bf16x8*)nb;
            B1 = *(const bf16x8*)(nb + 8);
            C0 = *(const bf16x8*)(nb + 16);
            C1 = *(const bf16x8*)(nb + 24);
        }
        const float dx = dt * x;
        float y = Dd * x;
#pragma unroll
        for (int n = 0; n < 8; ++n) {
            float e = fast_exp2(dt * A2[n]);
            h[n] = e * h[n] + (float)Bl[n] * dx;
            y += (float)Cl[n] * h[n];
        }
#pragma unroll
        for (int n = 0; n < 8; ++n) {
            float e = fast_exp2(dt * A2[n + 8]);
            h[n + 8] = e * h[n + 8] + (float)Bh[n] * dx;
            y += (float)Ch[n] * h[n + 8];
        }
        yp[(size_t)t * 2048] = (bf16)y;
    }
}

// ---------------------------------------------------------------------------
// launch.  Inputs: f32. Output: f32 (32 MiB).
// ws (>=64 MiB):
//   buf0 @0    (32Mi): xh -> delta -> y            (bf16)
//   buf1 @32Mi (32Mi): W_in_lo_b16 -> xc -> ry -> W_out_b16
// d_out (32 MiB, scratch until gemm7):
//   @0     dbc bf16 (1.5Mi)
//   @2Mi   gemm3 split-K partials f32 (12Mi)  ->  Hbuf f32 (8Mi, NC=16)
//          then after scan: W_in_hi_b16 (4Mi)
//   @10Mi  Abuf bf16 (4Mi)
//   @14Mi  W_x_b16 (384Ki) | @14.5Mi W_dt_b16 (256Ki)
//   @16Mi  x_b16 (16Mi, live until gemm6)
// ---------------------------------------------------------------------------
extern "C" void kernel_launch(void* const* d_in, const int* in_sizes, int n_in,
                              void* d_out, int out_size, void* d_ws, size_t ws_size,
                              hipStream_t stream)
{
    const float* x      = (const float*)d_in[0];
    const float* W_in   = (const float*)d_in[1];
    const float* conv_w = (const float*)d_in[2];
    const float* conv_b = (const float*)d_in[3];
    const float* W_x    = (const float*)d_in[4];
    const float* W_dt   = (const float*)d_in[5];
    const float* b_dt   = (const float*)d_in[6];
    const float* A_raw  = (const float*)d_in[7];
    const float* Dvec   = (const float*)d_in[8];
    const float* W_out  = (const float*)d_in[9];
    float* out = (float*)d_out;

    char* ws = (char*)d_ws;
    bf16*  buf0   = (bf16*)(ws + 0);           // xh -> delta -> y
    bf16*  buf1   = (bf16*)(ws + 33554432);    // W_in_lo -> xc -> ry -> W_out
    char*  dob    = (char*)d_out;
    bf16*  dbc    = (bf16*)dob;
    float* Pbuf   = (float*)(dob + 2097152);   // gemm3 partials (12Mi)
    float* Hbuf   = (float*)(dob + 2097152);   // scan H (8Mi), after reduce
    bf16*  Whi    = (bf16*)(dob + 2097152);    // W_in_hi (4Mi), after scan
    bf16*  Abuf   = (bf16*)(dob + 10485760);   // 4Mi
    bf16*  Wxb    = (bf16*)(dob + 14680064);   // 384Ki
    bf16*  Wdtb   = (bf16*)(dob + 15204352);   // 256Ki
    bf16*  xb     = (bf16*)(dob + 16777216);   // x bf16 (16Mi)
    bf16*  Wlo    = buf1;                       // W_in_lo (4Mi), pre-conv
    bf16*  Woutb  = buf1;                       // W_out (4Mi), post-gemm6

    // 0) one-time bf16 conversions
    cvt_bf16<<<dim3(4096), 256, 0, stream>>>(x, xb, 1048576);
    cvt_bf16<<<dim3(1024), 256, 0, stream>>>(W_in, Wlo, 262144);
    cvt_bf16<<<dim3(96),   256, 0, stream>>>(W_x, Wxb, 24576);
    cvt_bf16<<<dim3(64),   256, 0, stream>>>(W_dt, Wdtb, 16384);

    // 1) xh = x @ W_in[:2048]^T          M=8192 N=2048 K=1024
    gemm_bt<0, bf16><<<dim3(64, 16), 256, 0, stream>>>(
        xb, 1024, Wlo, 1024, buf0, 2048, 1024, 2048, nullptr, nullptr, 0);
    // 2) xc = silu(causal_conv(xh) + cb)
    conv_kernel<<<dim3(8192), 256, 0, stream>>>(buf0, conv_w, conv_b, buf1);
    // 3) dbc = xc @ W_x^T   M=8192 N=96 K=2048, split-K x4 -> f32 partials
    gemm_bt<0, float><<<dim3(64, 1, 4), 256, 0, stream>>>(
        buf1, 2048, Wxb, 2048, Pbuf, 96, 512, 96, nullptr, nullptr, 786432);
    reduce_dbc<<<dim3(768), 256, 0, stream>>>(Pbuf, dbc);
    // 4) delta = softplus(dt @ W_dt^T + b_dt)   (lda=96, K=64)
    gemm_bt<1, bf16><<<dim3(64, 16), 256, 0, stream>>>(
        dbc, 96, Wdtb, 64, buf0, 2048, 64, 2048, b_dt, nullptr, 0);
    // 5) chunk-parallel scan -> ry (ungated), in place over xc
    scan_p1<<<dim3(8, 4, 16), 256, 0, stream>>>(
        buf0, dbc, A_raw, buf1, Hbuf, Abuf);
    scan_p2<<<dim3(512), 256, 0, stream>>>(Hbuf, Abuf);
    scan_p3<<<dim3(8, 4, 16), 256, 0, stream>>>(
        buf0, dbc, A_raw, Dvec, Hbuf, buf1, buf1);
    // 6) y = ry * silu(x @ W_in[2048:]^T)   (fused z-GEMM + gate)
    cvt_bf16<<<dim3(1024), 256, 0, stream>>>(W_in + (size_t)2048 * 1024, Whi, 262144);
    gemm_bt<2, bf16><<<dim3(64, 16), 256, 0, stream>>>(
        xb, 1024, Whi, 1024, buf0, 2048, 1024, 2048, nullptr, buf1, 0);
    // 7) out = y @ W_out^T  (f32 store)  M=8192 N=1024 K=2048
    cvt_bf16<<<dim3(1024), 256, 0, stream>>>(W_out, Woutb, 262144);
    gemm_bt<0, float><<<dim3(64, 8), 256, 0, stream>>>(
        buf0, 2048, Woutb, 2048, out, 1024, 2048, 1024, nullptr, nullptr, 0);
}

// Round 3
// 493.432 us; speedup vs baseline: 1.8959x; 1.0532x over previous
//
#include <hip/hip_runtime.h>
#include <hip/hip_bf16.h>

typedef __bf16 bf16;
typedef __bf16 bf16x4 __attribute__((ext_vector_type(4)));
typedef __bf16 bf16x8 __attribute__((ext_vector_type(8)));
typedef float f32x4 __attribute__((ext_vector_type(4)));

__device__ __forceinline__ float fast_exp2(float x) {
#if __has_builtin(__builtin_amdgcn_exp2f)
    return __builtin_amdgcn_exp2f(x);
#else
    return exp2f(x);
#endif
}

// async global->LDS, 16B per lane. lds base must be wave-uniform; the HW
// writes lds + lane*16; the GLOBAL address is per-lane. (m97 pattern)
__device__ __forceinline__ void gload16(bf16* lds, const bf16* g) {
    __builtin_amdgcn_global_load_lds(
        (const __attribute__((address_space(1))) void*)g,
        (__attribute__((address_space(3))) void*)lds,
        16, 0, 0);
}

// ---------------------------------------------------------------------------
// f32 -> bf16 vectorized cast (8 elems / thread)
// ---------------------------------------------------------------------------
__device__ __forceinline__ bf16x8 cvt8(const float* p) {
    float4 a = *(const float4*)p;
    float4 b = *(const float4*)(p + 4);
    bf16x8 r;
    r[0] = (bf16)a.x; r[1] = (bf16)a.y; r[2] = (bf16)a.z; r[3] = (bf16)a.w;
    r[4] = (bf16)b.x; r[5] = (bf16)b.y; r[6] = (bf16)b.z; r[7] = (bf16)b.w;
    return r;
}

__global__ __launch_bounds__(256) void cvt_bf16(
    const float* __restrict__ in, bf16* __restrict__ out, int n8)
{
    int i = blockIdx.x * 256 + threadIdx.x;
    if (i < n8)
        *(bf16x8*)(out + (size_t)i * 8) = cvt8(in + (size_t)i * 8);
}

// ---------------------------------------------------------------------------
// C[M x N] = A[M x K] * B[N x K]^T   (A,B bf16; f32 accum; TC out)
// m97 structure: 128x128 tile, BK=32, linear LDS [128][32] (64B rows),
// global_load_lds dwordx4 staging (4 issues/thread/K-step), 2-barrier loop,
// 4 waves (2x2), each wave 4x4 of 16x16x32 MFMA.
// EPI==0: plain   EPI==1: softplus(acc + bias_f32[col])
// EPI==2: out = gmul_bf16[row,col] * silu(acc)
// grid.z splits K: block z computes K range [z*K, (z+1)*K), stores to
// C + z*zstride (f32 partials for split-K callers; zstride=0 otherwise).
// ---------------------------------------------------------------------------
template <int EPI, typename TC>
__global__ __launch_bounds__(256, 2) void gemm_bt(
    const bf16* __restrict__ A, int lda,
    const bf16* __restrict__ B, int ldb,
    TC* __restrict__ C, int ldc,
    int K, int Neff, const float* __restrict__ bias,
    const bf16* __restrict__ gmul, size_t zstride)
{
    __shared__ bf16 As[128 * 32];
    __shared__ bf16 Bs[128 * 32];

    const int tid  = threadIdx.x;
    const int lane = tid & 63;
    const int wave = tid >> 6;
    const int quad = lane >> 4;
    const int l16  = lane & 15;
    const int wm   = (wave >> 1) << 6;
    const int wn   = (wave & 1) << 6;
    const int bm   = blockIdx.x << 7;
    const int bn   = blockIdx.y << 7;
    const int kb   = blockIdx.z * K;

    // staging map: wave w covers LDS rows [w*16, +16)
    // lane l -> row +(l>>2), col (l&3)*8   (lds dest = uniform base + l*16B)
    const int srow = (wave << 4) + (lane >> 2);
    const int scol = (lane & 3) << 3;

    const bf16* Ag0 = A + (size_t)(bm + srow) * lda + kb + scol;
    const bf16* Ag1 = Ag0 + (size_t)lda * 64;
    int br0 = bn + srow;      br0 = br0 < Neff ? br0 : Neff - 1;
    int br1 = bn + srow + 64; br1 = br1 < Neff ? br1 : Neff - 1;
    const bf16* Bg0 = B + (size_t)br0 * ldb + kb + scol;
    const bf16* Bg1 = B + (size_t)br1 * ldb + kb + scol;

    bf16* Asd0 = As + wave * 512;           // wave-uniform LDS bases
    bf16* Asd1 = As + wave * 512 + 2048;
    bf16* Bsd0 = Bs + wave * 512;
    bf16* Bsd1 = Bs + wave * 512 + 2048;

    f32x4 acc[4][4] = {};

    for (int k0 = 0; k0 < K; k0 += 32) {
        if (k0) __syncthreads();            // protect LDS from overwrite
        gload16(Asd0, Ag0 + k0);
        gload16(Asd1, Ag1 + k0);
        gload16(Bsd0, Bg0 + k0);
        gload16(Bsd1, Bg1 + k0);
        __syncthreads();                    // drains vmcnt before barrier

        bf16x8 af[4], bfr[4];
#pragma unroll
        for (int i = 0; i < 4; ++i) {
            af[i]  = *(const bf16x8*)(As + (wm + i * 16 + l16) * 32 + quad * 8);
            bfr[i] = *(const bf16x8*)(Bs + (wn + i * 16 + l16) * 32 + quad * 8);
        }
#pragma unroll
        for (int mi = 0; mi < 4; ++mi)
#pragma unroll
            for (int ni = 0; ni < 4; ++ni)
                acc[mi][ni] = __builtin_amdgcn_mfma_f32_16x16x32_bf16(
                    af[mi], bfr[ni], acc[mi][ni], 0, 0, 0);
    }

    TC* Cz = C + (size_t)blockIdx.z * zstride;

    // C/D layout: row = quad*4 + r, col = l16  (m89-verified)
#pragma unroll
    for (int mi = 0; mi < 4; ++mi) {
        const int row = bm + wm + mi * 16 + quad * 4;
#pragma unroll
        for (int ni = 0; ni < 4; ++ni) {
            const int col = bn + wn + ni * 16 + l16;
            if (col < Neff) {
                float bc = (EPI == 1) ? bias[col] : 0.f;
#pragma unroll
                for (int r = 0; r < 4; ++r) {
                    float v = acc[mi][ni][r];
                    if (EPI == 1) {
                        v += bc;
                        v = (v > 15.f) ? v : log1pf(__expf(v));
                    } else if (EPI == 2) {
                        float g = v / (1.f + __expf(-v));   // silu(z)
                        v = (float)gmul[(size_t)(row + r) * ldc + col] * g;
                    }
                    Cz[(size_t)(row + r) * ldc + col] = (TC)v;
                }
            }
        }
    }
}

// ---------------------------------------------------------------------------
// split-K reduce: dbc[i] = bf16(sum_z P[z][i]),  n = 8192*96, 4 splits
// ---------------------------------------------------------------------------
__global__ __launch_bounds__(256) void reduce_dbc(
    const float* __restrict__ P, bf16* __restrict__ dbc)
{
    const size_t i = ((size_t)blockIdx.x * 256 + threadIdx.x) * 4;
    f32x4 s = *(const f32x4*)(P + i);
#pragma unroll
    for (int z = 1; z < 4; ++z) {
        f32x4 p = *(const f32x4*)(P + (size_t)z * 786432 + i);
        s[0] += p[0]; s[1] += p[1]; s[2] += p[2]; s[3] += p[3];
    }
    bf16x4 o;
    o[0] = (bf16)s[0]; o[1] = (bf16)s[1]; o[2] = (bf16)s[2]; o[3] = (bf16)s[3];
    *(bf16x4*)(dbc + i) = o;
}

// ---------------------------------------------------------------------------
// causal depthwise conv (k=4, left pad 3) + bias + SiLU: xh bf16 -> xc bf16
// t-tiled: each thread produces 8 consecutive t for 8 channels.
// Reads 11 rows per 8 outputs (1.375x) with reuse in registers; row t_in
// contributes to outputs local = r - j (r = row idx 0..10, j = tap 0..3).
// Block = (t-group of 8, batch); 256 threads cover all 2048 channels.
// ---------------------------------------------------------------------------
__global__ __launch_bounds__(256) void conv_kernel(
    const bf16* __restrict__ xh, const float* __restrict__ cw,
    const float* __restrict__ cb, bf16* __restrict__ xc)
{
    const int t0 = blockIdx.x << 3;          // 0..2040
    const int b  = blockIdx.y;
    const int d  = threadIdx.x * 8;

    float4 wv[8];           // wv[i] = taps 0..3 of channel d+i
#pragma unroll
    for (int i = 0; i < 8; ++i)
        wv[i] = *(const float4*)(cw + (d + i) * 4);

    float4 cb0 = *(const float4*)(cb + d);
    float4 cb1 = *(const float4*)(cb + d + 4);

    float acc[8][8];
#pragma unroll
    for (int k = 0; k < 8; ++k) {
        acc[k][0] = cb0.x; acc[k][1] = cb0.y; acc[k][2] = cb0.z; acc[k][3] = cb0.w;
        acc[k][4] = cb1.x; acc[k][5] = cb1.y; acc[k][6] = cb1.z; acc[k][7] = cb1.w;
    }

    const bf16* base = xh + ((size_t)b * 2048 + t0) * 2048 + d;

#pragma unroll
    for (int r = 0; r < 11; ++r) {
        const int t_in = t0 - 3 + r;
        if (t_in >= 0) {                     // uniform branch (t0 >= 8 always true)
            bf16x8 v = *(const bf16x8*)(base + (size_t)(r - 3) * 2048);
            float vf[8];
#pragma unroll
            for (int i = 0; i < 8; ++i) vf[i] = (float)v[i];
#pragma unroll
            for (int j = 0; j < 4; ++j) {    // tap j multiplies x[t-3+j]
                const int local = r - j;     // output index t0+local
                if (local >= 0 && local < 8) {
#pragma unroll
                    for (int i = 0; i < 8; ++i) {
                        float w = (j == 0) ? wv[i].x : (j == 1) ? wv[i].y
                                : (j == 2) ? wv[i].z : wv[i].w;
                        acc[local][i] += w * vf[i];
                    }
                }
            }
        }
    }

    bf16* ob = xc + ((size_t)b * 2048 + t0) * 2048 + d;
#pragma unroll
    for (int k = 0; k < 8; ++k) {
        bf16x8 o;
#pragma unroll
        for (int i = 0; i < 8; ++i) {
            float s = acc[k][i];
            o[i] = (bf16)(s / (1.f + __expf(-s)));
        }
        *(bf16x8*)(ob + (size_t)k * 2048) = o;
    }
}

// ---------------------------------------------------------------------------
// Chunk-parallel selective scan, NC=16 chunks x TC=128 t.
// Half-wave n-split: within each wave, lanes 0-31 handle states n=0..7 and
// lanes 32-63 handle n=8..15 for the SAME 32 d's.  Doubles the grid (1024
// blocks -> 4 blocks/CU, 50% occupancy cap) vs the 16-state-per-thread
// layout; h-chains stay thread-local; y-reduce is one __shfl_xor(y,32).
// x/dt loads of the two halves hit the same 64B line; B/C are per-half
// 16B broadcast loads.  Hbuf/Abuf layout: (b, c, d, n) -- unchanged.
// ---------------------------------------------------------------------------
__global__ __launch_bounds__(256, 4) void scan_p1(
    const bf16* __restrict__ delta, const bf16* __restrict__ dbc,
    const float* __restrict__ A_raw, const bf16* __restrict__ xc,
    float* __restrict__ Hbuf, bf16* __restrict__ Abuf)
{
    const int tid  = threadIdx.x;
    const int lane = tid & 63;
    const int wv   = tid >> 6;
    const int dl   = lane & 31;
    const int nh   = lane >> 5;              // state half: 0 -> n 0..7, 1 -> 8..15
    const int d    = (blockIdx.x << 7) + (wv << 5) + dl;
    const int b    = blockIdx.y;
    const int c    = blockIdx.z;

    float A2[8];            // A[nh*8+k] * log2(e)
#pragma unroll
    for (int k = 0; k < 8; ++k)
        A2[k] = -__expf(A_raw[(nh * 8 + k) * 2048 + d]) * 1.44269504f;

    float h[8];
#pragma unroll
    for (int k = 0; k < 8; ++k) h[k] = 0.f;
    float sdt = 0.f;

    const size_t xbase = ((size_t)(b * 2048 + c * 128)) * 2048 + d;
    const bf16* xp = xc + xbase;
    const bf16* dp = delta + xbase;
    const bf16* bp = dbc + ((size_t)(b * 2048 + c * 128)) * 96 + 64 + nh * 8;

    bf16 xr = xp[0], dr = dp[0];
    bf16x8 B0 = *(const bf16x8*)(bp);

#pragma unroll 4
    for (int t = 0; t < 128; ++t) {
        const float x  = (float)xr;
        const float dt = (float)dr;
        const bf16x8 Bl = B0;
        if (t < 127) {
            xr = xp[(size_t)(t + 1) * 2048];
            dr = dp[(size_t)(t + 1) * 2048];
            B0 = *(const bf16x8*)(bp + (size_t)(t + 1) * 96);
        }
        const float dx = dt * x;
        sdt += dt;
#pragma unroll
        for (int k = 0; k < 8; ++k) {
            float e = fast_exp2(dt * A2[k]);
            h[k] = e * h[k] + (float)Bl[k] * dx;
        }
    }

    const size_t hbase = (((size_t)b * 16 + c) * 2048 + d) * 16 + nh * 8;
    f32x4* Hp = (f32x4*)(Hbuf + hbase);
#pragma unroll
    for (int r = 0; r < 2; ++r) {
        f32x4 v;
        v[0] = h[r * 4]; v[1] = h[r * 4 + 1];
        v[2] = h[r * 4 + 2]; v[3] = h[r * 4 + 3];
        Hp[r] = v;
    }
    bf16x8 a0;
#pragma unroll
    for (int k = 0; k < 8; ++k)
        a0[k] = (bf16)fast_exp2(A2[k] * sdt);
    *(bf16x8*)(Abuf + hbase) = a0;
}

__global__ __launch_bounds__(256) void scan_p2(
    float* __restrict__ Hbuf, const bf16* __restrict__ Abuf)
{
    const int id  = blockIdx.x * 256 + threadIdx.x;   // 131072 = b*32768+(d*16+n)
    const int b   = id >> 15;
    const int rem = id & 32767;
    const size_t base = (size_t)b * 16 * 32768 + rem;  // chunk stride 32768

    float Hv[16]; bf16 Av[16];
#pragma unroll
    for (int c = 0; c < 16; ++c) {
        Hv[c] = Hbuf[base + (size_t)c * 32768];
        Av[c] = Abuf[base + (size_t)c * 32768];
    }
    float ht = Hv[0];                      // H~_0 = H_0 (already stored)
#pragma unroll
    for (int c = 1; c < 16; ++c) {
        ht = Hv[c] + (float)Av[c] * ht;
        Hbuf[base + (size_t)c * 32768] = ht;
    }
}

__global__ __launch_bounds__(256, 4) void scan_p3(
    const bf16* __restrict__ delta, const bf16* __restrict__ dbc,
    const float* __restrict__ A_raw, const float* __restrict__ Dvec,
    const float* __restrict__ Hbuf, const bf16* xc, bf16* ry)
{
    const int tid  = threadIdx.x;
    const int lane = tid & 63;
    const int wv   = tid >> 6;
    const int dl   = lane & 31;
    const int nh   = lane >> 5;
    const int d    = (blockIdx.x << 7) + (wv << 5) + dl;
    const int b    = blockIdx.y;
    const int c    = blockIdx.z;

    float A2[8];
#pragma unroll
    for (int k = 0; k < 8; ++k)
        A2[k] = -__expf(A_raw[(nh * 8 + k) * 2048 + d]) * 1.44269504f;
    const float Dd = Dvec[d];

    float h[8];
    if (c > 0) {
        const f32x4* Hp = (const f32x4*)(
            Hbuf + (((size_t)b * 16 + (c - 1)) * 2048 + d) * 16 + nh * 8);
#pragma unroll
        for (int r = 0; r < 2; ++r) {
            f32x4 v = Hp[r];
            h[r * 4] = v[0]; h[r * 4 + 1] = v[1];
            h[r * 4 + 2] = v[2]; h[r * 4 + 3] = v[3];
        }
    } else {
#pragma unroll
        for (int k = 0; k < 8; ++k) h[k] = 0.f;
    }

    const size_t xbase = ((size_t)(b * 2048 + c * 128)) * 2048 + d;
    const bf16* xp = xc + xbase;
    const bf16* dp = delta + xbase;
    const bf16* bp = dbc + ((size_t)(b * 2048 + c * 128)) * 96 + 64 + nh * 8;
    bf16* yp = ry + xbase;

    bf16 xr = xp[0], dr = dp[0];
    bf16x8 B0 = *(const bf16x8*)(bp);
    bf16x8 C0 = *(const bf16x8*)(bp + 16);

#pragma unroll 4
    for (int t = 0; t < 128; ++t) {
        const float x  = (float)xr;
        const float dt = (float)dr;
        const bf16x8 Bl = B0, Cl = C0;
        if (t < 127) {
            xr = xp[(size_t)(t + 1) * 2048];
            dr = dp[(size_t)(t + 1) * 2048];
            const bf16* nb = bp + (size_t)(t + 1) * 96;
            B0 = *(const bf16x8*)nb;
            C0 = *(const bf16x8*)(nb + 16);
        }
        const float dx = dt * x;
        float y = nh ? 0.f : Dd * x;        // D*x counted once
#pragma unroll
        for (int k = 0; k < 8; ++k) {
            float e = fast_exp2(dt * A2[k]);
            h[k] = e * h[k] + (float)Bl[k] * dx;
            y += (float)Cl[k] * h[k];
        }
        y += __shfl_xor(y, 32);             // combine the two state halves
        if (nh == 0)
            yp[(size_t)t * 2048] = (bf16)y;
    }
}

// ---------------------------------------------------------------------------
// launch.  Inputs: f32. Output: f32 (32 MiB).
// ws (>=64 MiB):
//   buf0 @0    (32Mi): xh -> delta -> y            (bf16)
//   buf1 @32Mi (32Mi): W_in_lo_b16 -> xc -> ry -> W_out_b16
// d_out (32 MiB, scratch until gemm7):
//   @0     dbc bf16 (1.5Mi)
//   @2Mi   gemm3 split-K partials f32 (12Mi)  ->  Hbuf f32 (8Mi, NC=16)
//          then after scan: W_in_hi_b16 (4Mi)
//   @10Mi  Abuf bf16 (4Mi)
//   @14Mi  W_x_b16 (384Ki) | @14.5Mi W_dt_b16 (256Ki)
//   @16Mi  x_b16 (16Mi, live until gemm6)
// ---------------------------------------------------------------------------
extern "C" void kernel_launch(void* const* d_in, const int* in_sizes, int n_in,
                              void* d_out, int out_size, void* d_ws, size_t ws_size,
                              hipStream_t stream)
{
    const float* x      = (const float*)d_in[0];
    const float* W_in   = (const float*)d_in[1];
    const float* conv_w = (const float*)d_in[2];
    const float* conv_b = (const float*)d_in[3];
    const float* W_x    = (const float*)d_in[4];
    const float* W_dt   = (const float*)d_in[5];
    const float* b_dt   = (const float*)d_in[6];
    const float* A_raw  = (const float*)d_in[7];
    const float* Dvec   = (const float*)d_in[8];
    const float* W_out  = (const float*)d_in[9];
    float* out = (float*)d_out;

    char* ws = (char*)d_ws;
    bf16*  buf0   = (bf16*)(ws + 0);           // xh -> delta -> y
    bf16*  buf1   = (bf16*)(ws + 33554432);    // W_in_lo -> xc -> ry -> W_out
    char*  dob    = (char*)d_out;
    bf16*  dbc    = (bf16*)dob;
    float* Pbuf   = (float*)(dob + 2097152);   // gemm3 partials (12Mi)
    float* Hbuf   = (float*)(dob + 2097152);   // scan H (8Mi), after reduce
    bf16*  Whi    = (bf16*)(dob + 2097152);    // W_in_hi (4Mi), after scan
    bf16*  Abuf   = (bf16*)(dob + 10485760);   // 4Mi
    bf16*  Wxb    = (bf16*)(dob + 14680064);   // 384Ki
    bf16*  Wdtb   = (bf16*)(dob + 15204352);   // 256Ki
    bf16*  xb     = (bf16*)(dob + 16777216);   // x bf16 (16Mi)
    bf16*  Wlo    = buf1;                       // W_in_lo (4Mi), pre-conv
    bf16*  Woutb  = buf1;                       // W_out (4Mi), post-gemm6

    // 0) one-time bf16 conversions
    cvt_bf16<<<dim3(4096), 256, 0, stream>>>(x, xb, 1048576);
    cvt_bf16<<<dim3(1024), 256, 0, stream>>>(W_in, Wlo, 262144);
    cvt_bf16<<<dim3(96),   256, 0, stream>>>(W_x, Wxb, 24576);
    cvt_bf16<<<dim3(64),   256, 0, stream>>>(W_dt, Wdtb, 16384);

    // 1) xh = x @ W_in[:2048]^T          M=8192 N=2048 K=1024
    gemm_bt<0, bf16><<<dim3(64, 16), 256, 0, stream>>>(
        xb, 1024, Wlo, 1024, buf0, 2048, 1024, 2048, nullptr, nullptr, 0);
    // 2) xc = silu(causal_conv(xh) + cb)
    conv_kernel<<<dim3(256, 4), 256, 0, stream>>>(buf0, conv_w, conv_b, buf1);
    // 3) dbc = xc @ W_x^T   M=8192 N=96 K=2048, split-K x4 -> f32 partials
    gemm_bt<0, float><<<dim3(64, 1, 4), 256, 0, stream>>>(
        buf1, 2048, Wxb, 2048, Pbuf, 96, 512, 96, nullptr, nullptr, 786432);
    reduce_dbc<<<dim3(768), 256, 0, stream>>>(Pbuf, dbc);
    // 4) delta = softplus(dt @ W_dt^T + b_dt)   (lda=96, K=64)
    gemm_bt<1, bf16><<<dim3(64, 16), 256, 0, stream>>>(
        dbc, 96, Wdtb, 64, buf0, 2048, 64, 2048, b_dt, nullptr, 0);
    // 5) chunk-parallel scan -> ry (ungated), in place over xc
    scan_p1<<<dim3(16, 4, 16), 256, 0, stream>>>(
        buf0, dbc, A_raw, buf1, Hbuf, Abuf);
    scan_p2<<<dim3(512), 256, 0, stream>>>(Hbuf, Abuf);
    scan_p3<<<dim3(16, 4, 16), 256, 0, stream>>>(
        buf0, dbc, A_raw, Dvec, Hbuf, buf1, buf1);
    // 6) y = ry * silu(x @ W_in[2048:]^T)   (fused z-GEMM + gate)
    cvt_bf16<<<dim3(1024), 256, 0, stream>>>(W_in + (size_t)2048 * 1024, Whi, 262144);
    gemm_bt<2, bf16><<<dim3(64, 16), 256, 0, stream>>>(
        xb, 1024, Whi, 1024, buf0, 2048, 1024, 2048, nullptr, buf1, 0);
    // 7) out = y @ W_out^T  (f32 store)  M=8192 N=1024 K=2048
    cvt_bf16<<<dim3(1024), 256, 0, stream>>>(W_out, Woutb, 262144);
    gemm_bt<0, float><<<dim3(64, 8), 256, 0, stream>>>(
        buf0, 2048, Woutb, 2048, out, 1024, 2048, 1024, nullptr, nullptr, 0);
}

// Round 4
// 487.785 us; speedup vs baseline: 1.9178x; 1.0116x over previous
//
#include <hip/hip_runtime.h>
#include <hip/hip_bf16.h>

typedef __bf16 bf16;
typedef __bf16 bf16x4 __attribute__((ext_vector_type(4)));
typedef __bf16 bf16x8 __attribute__((ext_vector_type(8)));
typedef float f32x4 __attribute__((ext_vector_type(4)));

__device__ __forceinline__ float fast_exp2(float x) {
#if __has_builtin(__builtin_amdgcn_exp2f)
    return __builtin_amdgcn_exp2f(x);
#else
    return exp2f(x);
#endif
}

// async global->LDS, 16B per lane. lds base must be wave-uniform; the HW
// writes lds + lane*16; the GLOBAL address is per-lane. (m97 pattern)
__device__ __forceinline__ void gload16(bf16* lds, const bf16* g) {
    __builtin_amdgcn_global_load_lds(
        (const __attribute__((address_space(1))) void*)g,
        (__attribute__((address_space(3))) void*)lds,
        16, 0, 0);
}

// ---------------------------------------------------------------------------
// f32 -> bf16 vectorized cast (8 elems / thread)
// ---------------------------------------------------------------------------
__device__ __forceinline__ bf16x8 cvt8(const float* p) {
    float4 a = *(const float4*)p;
    float4 b = *(const float4*)(p + 4);
    bf16x8 r;
    r[0] = (bf16)a.x; r[1] = (bf16)a.y; r[2] = (bf16)a.z; r[3] = (bf16)a.w;
    r[4] = (bf16)b.x; r[5] = (bf16)b.y; r[6] = (bf16)b.z; r[7] = (bf16)b.w;
    return r;
}

__global__ __launch_bounds__(256) void cvt_bf16(
    const float* __restrict__ in, bf16* __restrict__ out, int n8)
{
    int i = blockIdx.x * 256 + threadIdx.x;
    if (i < n8)
        *(bf16x8*)(out + (size_t)i * 8) = cvt8(in + (size_t)i * 8);
}

// ---------------------------------------------------------------------------
// C[M x N] = A[M x K] * B[N x K]^T   (A,B bf16; f32 accum; TC out)
// m97 structure: 128x128 tile, BK=32, linear LDS [128][32] (64B rows),
// global_load_lds dwordx4 staging (4 issues/thread/K-step), 2-barrier loop,
// 4 waves (2x2), each wave 4x4 of 16x16x32 MFMA.
// EPI==0: plain   EPI==1: softplus(acc + bias_f32[col])
// EPI==2: out = gmul_bf16[row,col] * silu(acc)
// grid.z splits K: block z computes K range [z*K, (z+1)*K), stores to
// C + z*zstride (f32 partials for split-K callers; zstride=0 otherwise).
// ---------------------------------------------------------------------------
template <int EPI, typename TC>
__global__ __launch_bounds__(256, 2) void gemm_bt(
    const bf16* __restrict__ A, int lda,
    const bf16* __restrict__ B, int ldb,
    TC* __restrict__ C, int ldc,
    int K, int Neff, const float* __restrict__ bias,
    const bf16* __restrict__ gmul, size_t zstride)
{
    __shared__ bf16 As[128 * 32];
    __shared__ bf16 Bs[128 * 32];

    const int tid  = threadIdx.x;
    const int lane = tid & 63;
    const int wave = tid >> 6;
    const int quad = lane >> 4;
    const int l16  = lane & 15;
    const int wm   = (wave >> 1) << 6;
    const int wn   = (wave & 1) << 6;
    const int bm   = blockIdx.x << 7;
    const int bn   = blockIdx.y << 7;
    const int kb   = blockIdx.z * K;

    // staging map: wave w covers LDS rows [w*16, +16)
    // lane l -> row +(l>>2), col (l&3)*8   (lds dest = uniform base + l*16B)
    const int srow = (wave << 4) + (lane >> 2);
    const int scol = (lane & 3) << 3;

    const bf16* Ag0 = A + (size_t)(bm + srow) * lda + kb + scol;
    const bf16* Ag1 = Ag0 + (size_t)lda * 64;
    int br0 = bn + srow;      br0 = br0 < Neff ? br0 : Neff - 1;
    int br1 = bn + srow + 64; br1 = br1 < Neff ? br1 : Neff - 1;
    const bf16* Bg0 = B + (size_t)br0 * ldb + kb + scol;
    const bf16* Bg1 = B + (size_t)br1 * ldb + kb + scol;

    bf16* Asd0 = As + wave * 512;           // wave-uniform LDS bases
    bf16* Asd1 = As + wave * 512 + 2048;
    bf16* Bsd0 = Bs + wave * 512;
    bf16* Bsd1 = Bs + wave * 512 + 2048;

    f32x4 acc[4][4] = {};

    for (int k0 = 0; k0 < K; k0 += 32) {
        if (k0) __syncthreads();            // protect LDS from overwrite
        gload16(Asd0, Ag0 + k0);
        gload16(Asd1, Ag1 + k0);
        gload16(Bsd0, Bg0 + k0);
        gload16(Bsd1, Bg1 + k0);
        __syncthreads();                    // drains vmcnt before barrier

        bf16x8 af[4], bfr[4];
#pragma unroll
        for (int i = 0; i < 4; ++i) {
            af[i]  = *(const bf16x8*)(As + (wm + i * 16 + l16) * 32 + quad * 8);
            bfr[i] = *(const bf16x8*)(Bs + (wn + i * 16 + l16) * 32 + quad * 8);
        }
#pragma unroll
        for (int mi = 0; mi < 4; ++mi)
#pragma unroll
            for (int ni = 0; ni < 4; ++ni)
                acc[mi][ni] = __builtin_amdgcn_mfma_f32_16x16x32_bf16(
                    af[mi], bfr[ni], acc[mi][ni], 0, 0, 0);
    }

    TC* Cz = C + (size_t)blockIdx.z * zstride;

    // C/D layout: row = quad*4 + r, col = l16  (m89-verified)
#pragma unroll
    for (int mi = 0; mi < 4; ++mi) {
        const int row = bm + wm + mi * 16 + quad * 4;
#pragma unroll
        for (int ni = 0; ni < 4; ++ni) {
            const int col = bn + wn + ni * 16 + l16;
            if (col < Neff) {
                float bc = (EPI == 1) ? bias[col] : 0.f;
#pragma unroll
                for (int r = 0; r < 4; ++r) {
                    float v = acc[mi][ni][r];
                    if (EPI == 1) {
                        v += bc;
                        v = (v > 15.f) ? v : log1pf(__expf(v));
                    } else if (EPI == 2) {
                        float g = v / (1.f + __expf(-v));   // silu(z)
                        v = (float)gmul[(size_t)(row + r) * ldc + col] * g;
                    }
                    Cz[(size_t)(row + r) * ldc + col] = (TC)v;
                }
            }
        }
    }
}

// ---------------------------------------------------------------------------
// split-K reduce: dbc[i] = bf16(sum_z P[z][i]),  n = 8192*96, 4 splits
// ---------------------------------------------------------------------------
__global__ __launch_bounds__(256) void reduce_dbc(
    const float* __restrict__ P, bf16* __restrict__ dbc)
{
    const size_t i = ((size_t)blockIdx.x * 256 + threadIdx.x) * 4;
    f32x4 s = *(const f32x4*)(P + i);
#pragma unroll
    for (int z = 1; z < 4; ++z) {
        f32x4 p = *(const f32x4*)(P + (size_t)z * 786432 + i);
        s[0] += p[0]; s[1] += p[1]; s[2] += p[2]; s[3] += p[3];
    }
    bf16x4 o;
    o[0] = (bf16)s[0]; o[1] = (bf16)s[1]; o[2] = (bf16)s[2]; o[3] = (bf16)s[3];
    *(bf16x4*)(dbc + i) = o;
}

// ---------------------------------------------------------------------------
// causal depthwise conv (k=4, left pad 3) + bias + SiLU: xh bf16 -> xc bf16
// t-tiled: each thread produces 8 consecutive t for 8 channels.
// ---------------------------------------------------------------------------
__global__ __launch_bounds__(256) void conv_kernel(
    const bf16* __restrict__ xh, const float* __restrict__ cw,
    const float* __restrict__ cb, bf16* __restrict__ xc)
{
    const int t0 = blockIdx.x << 3;          // 0..2040
    const int b  = blockIdx.y;
    const int d  = threadIdx.x * 8;

    float4 wv[8];           // wv[i] = taps 0..3 of channel d+i
#pragma unroll
    for (int i = 0; i < 8; ++i)
        wv[i] = *(const float4*)(cw + (d + i) * 4);

    float4 cb0 = *(const float4*)(cb + d);
    float4 cb1 = *(const float4*)(cb + d + 4);

    float acc[8][8];
#pragma unroll
    for (int k = 0; k < 8; ++k) {
        acc[k][0] = cb0.x; acc[k][1] = cb0.y; acc[k][2] = cb0.z; acc[k][3] = cb0.w;
        acc[k][4] = cb1.x; acc[k][5] = cb1.y; acc[k][6] = cb1.z; acc[k][7] = cb1.w;
    }

    const bf16* base = xh + ((size_t)b * 2048 + t0) * 2048 + d;

#pragma unroll
    for (int r = 0; r < 11; ++r) {
        const int t_in = t0 - 3 + r;
        if (t_in >= 0) {                     // uniform branch
            bf16x8 v = *(const bf16x8*)(base + (size_t)(r - 3) * 2048);
            float vf[8];
#pragma unroll
            for (int i = 0; i < 8; ++i) vf[i] = (float)v[i];
#pragma unroll
            for (int j = 0; j < 4; ++j) {    // tap j multiplies x[t-3+j]
                const int local = r - j;     // output index t0+local
                if (local >= 0 && local < 8) {
#pragma unroll
                    for (int i = 0; i < 8; ++i) {
                        float w = (j == 0) ? wv[i].x : (j == 1) ? wv[i].y
                                : (j == 2) ? wv[i].z : wv[i].w;
                        acc[local][i] += w * vf[i];
                    }
                }
            }
        }
    }

    bf16* ob = xc + ((size_t)b * 2048 + t0) * 2048 + d;
#pragma unroll
    for (int k = 0; k < 8; ++k) {
        bf16x8 o;
#pragma unroll
        for (int i = 0; i < 8; ++i) {
            float s = acc[k][i];
            o[i] = (bf16)(s / (1.f + __expf(-s)));
        }
        *(bf16x8*)(ob + (size_t)k * 2048) = o;
    }
}

// ---------------------------------------------------------------------------
// Chunk-parallel selective scan, NC=16 chunks x TC=128 t.
// thread = (b, c, d); all 16 states n in registers.  Latency is hidden by
// ILP: groups of 4 t-steps, double-buffered (group g+1's 8 scalar + 8
// vector loads in flight while group g computes ~500-900 cy of VALU).
// Half-wave split tried r3: WORSE (duplicated x/dt loads + per-t shuffle).
// Hbuf/Abuf layout: (b, c, d, n).
// ---------------------------------------------------------------------------
__global__ __launch_bounds__(256, 2) void scan_p1(
    const bf16* __restrict__ delta, const bf16* __restrict__ dbc,
    const float* __restrict__ A_raw, const bf16* __restrict__ xc,
    float* __restrict__ Hbuf, bf16* __restrict__ Abuf)
{
    const int d = (blockIdx.x << 8) + threadIdx.x;
    const int b = blockIdx.y;
    const int c = blockIdx.z;

    float A2[16];           // A[n] * log2(e)
#pragma unroll
    for (int n = 0; n < 16; ++n)
        A2[n] = -__expf(A_raw[n * 2048 + d]) * 1.44269504f;

    float h[16];
#pragma unroll
    for (int n = 0; n < 16; ++n) h[n] = 0.f;
    float sdt = 0.f;

    const size_t xbase = ((size_t)(b * 2048 + c * 128)) * 2048 + d;
    const bf16* xp = xc + xbase;
    const bf16* dp = delta + xbase;
    const bf16* bp = dbc + ((size_t)(b * 2048 + c * 128)) * 96 + 64;

    bf16 xA[4], dA[4], xB[4], dB[4];
    bf16x8 BA[4][2], BB[4][2];

#define LG1(X, D, Bv, g) do {                                       \
    _Pragma("unroll")                                               \
    for (int j = 0; j < 4; ++j) {                                   \
        const size_t tt = (size_t)((g) * 4 + j);                    \
        X[j] = xp[tt * 2048];                                       \
        D[j] = dp[tt * 2048];                                       \
        const bf16* nb = bp + tt * 96;                              \
        Bv[j][0] = *(const bf16x8*)nb;                              \
        Bv[j][1] = *(const bf16x8*)(nb + 8);                        \
    } } while (0)

#define CG1(X, D, Bv) do {                                          \
    _Pragma("unroll")                                               \
    for (int j = 0; j < 4; ++j) {                                   \
        const float x  = (float)X[j];                               \
        const float dt = (float)D[j];                               \
        const float dx = dt * x;                                    \
        sdt += dt;                                                  \
        _Pragma("unroll")                                           \
        for (int k = 0; k < 8; ++k) {                               \
            float e = fast_exp2(dt * A2[k]);                        \
            h[k] = e * h[k] + (float)Bv[j][0][k] * dx;              \
        }                                                           \
        _Pragma("unroll")                                           \
        for (int k = 0; k < 8; ++k) {                               \
            float e = fast_exp2(dt * A2[k + 8]);                    \
            h[k + 8] = e * h[k + 8] + (float)Bv[j][1][k] * dx;      \
        }                                                           \
    } } while (0)

    LG1(xA, dA, BA, 0);
#pragma unroll 1
    for (int g = 0; g < 32; g += 2) {
        LG1(xB, dB, BB, g + 1);
        CG1(xA, dA, BA);
        if (g + 2 < 32) LG1(xA, dA, BA, g + 2);
        CG1(xB, dB, BB);
    }
#undef LG1
#undef CG1

    const size_t hbase = (((size_t)b * 16 + c) * 2048 + d) * 16;
    f32x4* Hp = (f32x4*)(Hbuf + hbase);
#pragma unroll
    for (int r = 0; r < 4; ++r) {
        f32x4 v;
        v[0] = h[r * 4]; v[1] = h[r * 4 + 1];
        v[2] = h[r * 4 + 2]; v[3] = h[r * 4 + 3];
        Hp[r] = v;
    }
    bf16x8 a0, a1;
#pragma unroll
    for (int n = 0; n < 8; ++n) {
        a0[n] = (bf16)fast_exp2(A2[n] * sdt);
        a1[n] = (bf16)fast_exp2(A2[n + 8] * sdt);
    }
    *(bf16x8*)(Abuf + hbase) = a0;
    *(bf16x8*)(Abuf + hbase + 8) = a1;
}

__global__ __launch_bounds__(256) void scan_p2(
    float* __restrict__ Hbuf, const bf16* __restrict__ Abuf)
{
    const int id  = blockIdx.x * 256 + threadIdx.x;   // 131072 = b*32768+(d*16+n)
    const int b   = id >> 15;
    const int rem = id & 32767;
    const size_t base = (size_t)b * 16 * 32768 + rem;  // chunk stride 32768

    float Hv[16]; bf16 Av[16];
#pragma unroll
    for (int c = 0; c < 16; ++c) {
        Hv[c] = Hbuf[base + (size_t)c * 32768];
        Av[c] = Abuf[base + (size_t)c * 32768];
    }
    float ht = Hv[0];                      // H~_0 = H_0 (already stored)
#pragma unroll
    for (int c = 1; c < 16; ++c) {
        ht = Hv[c] + (float)Av[c] * ht;
        Hbuf[base + (size_t)c * 32768] = ht;
    }
}

__global__ __launch_bounds__(256, 2) void scan_p3(
    const bf16* __restrict__ delta, const bf16* __restrict__ dbc,
    const float* __restrict__ A_raw, const float* __restrict__ Dvec,
    const float* __restrict__ Hbuf, const bf16* xc, bf16* ry)
{
    const int d = (blockIdx.x << 8) + threadIdx.x;
    const int b = blockIdx.y;
    const int c = blockIdx.z;

    float A2[16];
#pragma unroll
    for (int n = 0; n < 16; ++n)
        A2[n] = -__expf(A_raw[n * 2048 + d]) * 1.44269504f;
    const float Dd = Dvec[d];

    float h[16];
    if (c > 0) {
        const f32x4* Hp = (const f32x4*)(
            Hbuf + (((size_t)b * 16 + (c - 1)) * 2048 + d) * 16);
#pragma unroll
        for (int r = 0; r < 4; ++r) {
            f32x4 v = Hp[r];
            h[r * 4] = v[0]; h[r * 4 + 1] = v[1];
            h[r * 4 + 2] = v[2]; h[r * 4 + 3] = v[3];
        }
    } else {
#pragma unroll
        for (int n = 0; n < 16; ++n) h[n] = 0.f;
    }

    const size_t xbase = ((size_t)(b * 2048 + c * 128)) * 2048 + d;
    const bf16* xp = xc + xbase;
    const bf16* dp = delta + xbase;
    const bf16* bp = dbc + ((size_t)(b * 2048 + c * 128)) * 96 + 64;
    bf16* yp = ry + xbase;

    bf16 xA[4], dA[4], xB[4], dB[4];
    bf16x8 BA[4][2], CA[4][2], BB[4][2], CB[4][2];

#define LG3(X, D, Bv, Cv, g) do {                                   \
    _Pragma("unroll")                                               \
    for (int j = 0; j < 4; ++j) {                                   \
        const size_t tt = (size_t)((g) * 4 + j);                    \
        X[j] = xp[tt * 2048];                                       \
        D[j] = dp[tt * 2048];                                       \
        const bf16* nb = bp + tt * 96;                              \
        Bv[j][0] = *(const bf16x8*)nb;                              \
        Bv[j][1] = *(const bf16x8*)(nb + 8);                        \
        Cv[j][0] = *(const bf16x8*)(nb + 16);                       \
        Cv[j][1] = *(const bf16x8*)(nb + 24);                       \
    } } while (0)

#define CG3(X, D, Bv, Cv, g) do {                                   \
    _Pragma("unroll")                                               \
    for (int j = 0; j < 4; ++j) {                                   \
        const float x  = (float)X[j];                               \
        const float dt = (float)D[j];                               \
        const float dx = dt * x;                                    \
        float y = Dd * x;                                           \
        _Pragma("unroll")                                           \
        for (int k = 0; k < 8; ++k) {                               \
            float e = fast_exp2(dt * A2[k]);                        \
            h[k] = e * h[k] + (float)Bv[j][0][k] * dx;              \
            y += (float)Cv[j][0][k] * h[k];                         \
        }                                                           \
        _Pragma("unroll")                                           \
        for (int k = 0; k < 8; ++k) {                               \
            float e = fast_exp2(dt * A2[k + 8]);                    \
            h[k + 8] = e * h[k + 8] + (float)Bv[j][1][k] * dx;      \
            y += (float)Cv[j][1][k] * h[k + 8];                     \
        }                                                           \
        yp[(size_t)((g) * 4 + j) * 2048] = (bf16)y;                 \
    } } while (0)

    LG3(xA, dA, BA, CA, 0);
#pragma unroll 1
    for (int g = 0; g < 32; g += 2) {
        LG3(xB, dB, BB, CB, g + 1);
        CG3(xA, dA, BA, CA, g);
        if (g + 2 < 32) LG3(xA, dA, BA, CA, g + 2);
        CG3(xB, dB, BB, CB, g + 1);
    }
#undef LG3
#undef CG3
}

// ---------------------------------------------------------------------------
// launch.  Inputs: f32. Output: f32 (32 MiB).
// ws (>=64 MiB):
//   buf0 @0    (32Mi): xh -> delta -> y            (bf16)
//   buf1 @32Mi (32Mi): W_in_lo_b16 -> xc -> ry -> W_out_b16
// d_out (32 MiB, scratch until gemm7):
//   @0     dbc bf16 (1.5Mi)
//   @2Mi   gemm3 split-K partials f32 (12Mi)  ->  Hbuf f32 (8Mi, NC=16)
//          then after scan: W_in_hi_b16 (4Mi)
//   @10Mi  Abuf bf16 (4Mi)
//   @14Mi  W_x_b16 (384Ki) | @14.5Mi W_dt_b16 (256Ki)
//   @16Mi  x_b16 (16Mi, live until gemm6)
// ---------------------------------------------------------------------------
extern "C" void kernel_launch(void* const* d_in, const int* in_sizes, int n_in,
                              void* d_out, int out_size, void* d_ws, size_t ws_size,
                              hipStream_t stream)
{
    const float* x      = (const float*)d_in[0];
    const float* W_in   = (const float*)d_in[1];
    const float* conv_w = (const float*)d_in[2];
    const float* conv_b = (const float*)d_in[3];
    const float* W_x    = (const float*)d_in[4];
    const float* W_dt   = (const float*)d_in[5];
    const float* b_dt   = (const float*)d_in[6];
    const float* A_raw  = (const float*)d_in[7];
    const float* Dvec   = (const float*)d_in[8];
    const float* W_out  = (const float*)d_in[9];
    float* out = (float*)d_out;

    char* ws = (char*)d_ws;
    bf16*  buf0   = (bf16*)(ws + 0);           // xh -> delta -> y
    bf16*  buf1   = (bf16*)(ws + 33554432);    // W_in_lo -> xc -> ry -> W_out
    char*  dob    = (char*)d_out;
    bf16*  dbc    = (bf16*)dob;
    float* Pbuf   = (float*)(dob + 2097152);   // gemm3 partials (12Mi)
    float* Hbuf   = (float*)(dob + 2097152);   // scan H (8Mi), after reduce
    bf16*  Whi    = (bf16*)(dob + 2097152);    // W_in_hi (4Mi), after scan
    bf16*  Abuf   = (bf16*)(dob + 10485760);   // 4Mi
    bf16*  Wxb    = (bf16*)(dob + 14680064);   // 384Ki
    bf16*  Wdtb   = (bf16*)(dob + 15204352);   // 256Ki
    bf16*  xb     = (bf16*)(dob + 16777216);   // x bf16 (16Mi)
    bf16*  Wlo    = buf1;                       // W_in_lo (4Mi), pre-conv
    bf16*  Woutb  = buf1;                       // W_out (4Mi), post-gemm6

    // 0) one-time bf16 conversions
    cvt_bf16<<<dim3(4096), 256, 0, stream>>>(x, xb, 1048576);
    cvt_bf16<<<dim3(1024), 256, 0, stream>>>(W_in, Wlo, 262144);
    cvt_bf16<<<dim3(96),   256, 0, stream>>>(W_x, Wxb, 24576);
    cvt_bf16<<<dim3(64),   256, 0, stream>>>(W_dt, Wdtb, 16384);

    // 1) xh = x @ W_in[:2048]^T          M=8192 N=2048 K=1024
    gemm_bt<0, bf16><<<dim3(64, 16), 256, 0, stream>>>(
        xb, 1024, Wlo, 1024, buf0, 2048, 1024, 2048, nullptr, nullptr, 0);
    // 2) xc = silu(causal_conv(xh) + cb)
    conv_kernel<<<dim3(256, 4), 256, 0, stream>>>(buf0, conv_w, conv_b, buf1);
    // 3) dbc = xc @ W_x^T   M=8192 N=96 K=2048, split-K x4 -> f32 partials
    gemm_bt<0, float><<<dim3(64, 1, 4), 256, 0, stream>>>(
        buf1, 2048, Wxb, 2048, Pbuf, 96, 512, 96, nullptr, nullptr, 786432);
    reduce_dbc<<<dim3(768), 256, 0, stream>>>(Pbuf, dbc);
    // 4) delta = softplus(dt @ W_dt^T + b_dt)   (lda=96, K=64)
    gemm_bt<1, bf16><<<dim3(64, 16), 256, 0, stream>>>(
        dbc, 96, Wdtb, 64, buf0, 2048, 64, 2048, b_dt, nullptr, 0);
    // 5) chunk-parallel scan -> ry (ungated), in place over xc
    scan_p1<<<dim3(8, 4, 16), 256, 0, stream>>>(
        buf0, dbc, A_raw, buf1, Hbuf, Abuf);
    scan_p2<<<dim3(512), 256, 0, stream>>>(Hbuf, Abuf);
    scan_p3<<<dim3(8, 4, 16), 256, 0, stream>>>(
        buf0, dbc, A_raw, Dvec, Hbuf, buf1, buf1);
    // 6) y = ry * silu(x @ W_in[2048:]^T)   (fused z-GEMM + gate)
    cvt_bf16<<<dim3(1024), 256, 0, stream>>>(W_in + (size_t)2048 * 1024, Whi, 262144);
    gemm_bt<2, bf16><<<dim3(64, 16), 256, 0, stream>>>(
        xb, 1024, Whi, 1024, buf0, 2048, 1024, 2048, nullptr, buf1, 0);
    // 7) out = y @ W_out^T  (f32 store)  M=8192 N=1024 K=2048
    cvt_bf16<<<dim3(1024), 256, 0, stream>>>(W_out, Woutb, 262144);
    gemm_bt<0, float><<<dim3(64, 8), 256, 0, stream>>>(
        buf0, 2048, Woutb, 2048, out, 1024, 2048, 1024, nullptr, nullptr, 0);
}